// Round 13
// baseline (484.385 us; speedup 1.0000x reference)
//
#include <hip/hip_runtime.h>
#include <math.h>

// Problem constants (fixed by the reference)
#define Bc   4
#define Tt   2048
#define HIDc 1024
#define NHc  16
#define HSc  64
#define BTc  (Bc * Tt)          // 8192
#define QSCALE 0.18033688011112042f   // 0.125 * log2(e): folded into q so exp(s/8)=2^acc

typedef __attribute__((ext_vector_type(8))) short bf16x8;   // 8 bf16 = 4 VGPRs
typedef __attribute__((ext_vector_type(4))) float f32x4;

__device__ __forceinline__ unsigned short f2bf(float f) {
    unsigned u = __float_as_uint(f);
    u = u + 0x7FFFu + ((u >> 16) & 1u);   // round-to-nearest-even
    return (unsigned short)(u >> 16);
}

__device__ __forceinline__ float fexp2(float x) {
#if __has_builtin(__builtin_amdgcn_exp2f)
    return __builtin_amdgcn_exp2f(x);
#else
    float r; asm("v_exp_f32 %0, %1" : "=v"(r) : "v"(x)); return r;
#endif
}

// lgkm-only barrier: global loads stay in flight across it.
__device__ __forceinline__ void bar_lgkm() {
    asm volatile("s_waitcnt lgkmcnt(0)" ::: "memory");
    __builtin_amdgcn_s_barrier();
    __builtin_amdgcn_sched_barrier(0);
}

// ---------------------------------------------------------------------------
// fp32 GEMM (Wo epilogue): C = A @ B + bias, 64x64 tile.
// ---------------------------------------------------------------------------
__global__ __launch_bounds__(256) void gemm_f32(
    const float* __restrict__ A, const float* __restrict__ Bm,
    const float* __restrict__ bias, float* __restrict__ C,
    int M, int N, int K)
{
    __shared__ float As[16][64];
    __shared__ float Bs[16][64];

    const int tid  = threadIdx.x;
    const int tx   = tid & 15;
    const int ty   = tid >> 4;
    const int row0 = blockIdx.y * 64;
    const int col0 = blockIdx.x * 64;

    const int la_r = tid >> 2;
    const int la_c = (tid & 3) << 2;
    const int lb_r = tid >> 4;
    const int lb_c = (tid & 15) << 2;

    float acc[4][4] = {};

    for (int k0 = 0; k0 < K; k0 += 16) {
        float4 av = *(const float4*)&A[(long)(row0 + la_r) * K + k0 + la_c];
        float4 bv = *(const float4*)&Bm[(long)(k0 + lb_r) * N + col0 + lb_c];
        __syncthreads();
        As[la_c + 0][la_r] = av.x;
        As[la_c + 1][la_r] = av.y;
        As[la_c + 2][la_r] = av.z;
        As[la_c + 3][la_r] = av.w;
        *(float4*)&Bs[lb_r][lb_c] = bv;
        __syncthreads();
#pragma unroll
        for (int kk = 0; kk < 16; ++kk) {
            float4 a = *(float4*)&As[kk][ty << 2];
            float4 b = *(float4*)&Bs[kk][tx << 2];
            float ar[4] = {a.x, a.y, a.z, a.w};
            float br[4] = {b.x, b.y, b.z, b.w};
#pragma unroll
            for (int i = 0; i < 4; ++i)
#pragma unroll
                for (int j = 0; j < 4; ++j)
                    acc[i][j] = fmaf(ar[i], br[j], acc[i][j]);
        }
    }

    float4 bvv = make_float4(0.f, 0.f, 0.f, 0.f);
    if (bias) bvv = *(const float4*)&bias[col0 + (tx << 2)];
#pragma unroll
    for (int i = 0; i < 4; ++i) {
        int m = row0 + (ty << 2) + i;
        float4 o;
        o.x = acc[i][0] + bvv.x;
        o.y = acc[i][1] + bvv.y;
        o.z = acc[i][2] + bvv.z;
        o.w = acc[i][3] + bvv.w;
        *(float4*)&C[(long)m * N + col0 + (tx << 2)] = o;
    }
}

// ---------------------------------------------------------------------------
__global__ __launch_bounds__(256) void init_bias64(
    float* __restrict__ C, const float* __restrict__ bias, long n)
{
    long idx = (long)blockIdx.x * 256 + threadIdx.x;
    if (idx < n) C[idx] = bias ? bias[idx & 63] : 0.f;
}

// ---------------------------------------------------------------------------
__global__ __launch_bounds__(256) void cast_bf16(
    const float* __restrict__ src, unsigned short* __restrict__ dst, long n)
{
    long i = ((long)blockIdx.x * 256 + threadIdx.x) * 4;
    if (i >= n) return;
    float4 v = *(const float4*)&src[i];
    ushort4 o;
    o.x = f2bf(v.x); o.y = f2bf(v.y); o.z = f2bf(v.z); o.w = f2bf(v.w);
    *(ushort4*)&dst[i] = o;
}

// ---------------------------------------------------------------------------
__global__ __launch_bounds__(256) void transpose_cast(
    const float* __restrict__ W, unsigned short* __restrict__ Wt, int R, int C)
{
    __shared__ float t[32][33];
    const int k0 = blockIdx.x * 32, n0 = blockIdx.y * 32;
    const int c = threadIdx.x & 31, r = threadIdx.x >> 5;  // r: 0..7
#pragma unroll
    for (int rr = r; rr < 32; rr += 8)
        t[rr][c] = W[(long)(k0 + rr) * C + n0 + c];
    __syncthreads();
#pragma unroll
    for (int rr = r; rr < 32; rr += 8)
        Wt[(long)(n0 + rr) * R + k0 + c] = f2bf(t[c][rr]);
}

// ---------------------------------------------------------------------------
// bf16 MFMA GEMM, B^T input. hm=1: head-major output (NH, B*T, HS).
// ---------------------------------------------------------------------------
__global__ __launch_bounds__(256) void gemm_bt_bf16(
    const unsigned short* __restrict__ A, const unsigned short* __restrict__ Bt,
    const float* __restrict__ bias, unsigned short* __restrict__ C,
    int M, int N, int K, float oscale, int hm)
{
    __shared__ unsigned short As[128][72];
    __shared__ unsigned short Bs[128][72];

    const int gid = blockIdx.x;
    const int xcd = gid & 7, ii = gid >> 3;          // ii: 0..63
    const int row0 = (xcd * 8 + (ii >> 3)) * 128;    // row-tile 0..63
    const int col0 = (ii & 7) * 128;                 // col-tile 0..7

    const int tid  = threadIdx.x;
    const int w  = tid >> 6, L = tid & 63;
    const int wm = (w & 1) * 64, wn = (w >> 1) * 64;
    const int lr = tid >> 3;
    const int lc = (tid & 7) * 8;
    const int ml = L & 15, q8 = (L >> 4) * 8, q4 = (L >> 4) * 4;

    f32x4 acc[4][4];
#pragma unroll
    for (int i = 0; i < 4; ++i)
#pragma unroll
        for (int j = 0; j < 4; ++j)
            acc[i][j] = (f32x4){0.f, 0.f, 0.f, 0.f};

    for (int k0 = 0; k0 < K; k0 += 64) {
        __syncthreads();
#pragma unroll
        for (int rr = 0; rr < 128; rr += 32) {
            *(float4*)&As[lr + rr][lc] = *(const float4*)&A[(long)(row0 + lr + rr) * K + k0 + lc];
            *(float4*)&Bs[lr + rr][lc] = *(const float4*)&Bt[(long)(col0 + lr + rr) * K + k0 + lc];
        }
        __syncthreads();
#pragma unroll
        for (int kk = 0; kk < 64; kk += 32) {
            bf16x8 a[4], b[4];
#pragma unroll
            for (int i = 0; i < 4; ++i) a[i] = *(bf16x8*)&As[wm + i * 16 + ml][kk + q8];
#pragma unroll
            for (int j = 0; j < 4; ++j) b[j] = *(bf16x8*)&Bs[wn + j * 16 + ml][kk + q8];
#pragma unroll
            for (int i = 0; i < 4; ++i)
#pragma unroll
                for (int j = 0; j < 4; ++j)
                    acc[i][j] = __builtin_amdgcn_mfma_f32_16x16x32_bf16(a[i], b[j], acc[i][j], 0, 0, 0);
        }
    }

#pragma unroll
    for (int j = 0; j < 4; ++j) {
        const int col = col0 + wn + j * 16 + ml;
        const float bj = bias ? bias[col] : 0.f;
#pragma unroll
        for (int i = 0; i < 4; ++i) {
#pragma unroll
            for (int r = 0; r < 4; ++r) {
                const int row = row0 + wm + i * 16 + q4 + r;
                const long idx = hm ? (((long)(col >> 6) * M + row) * HSc + (col & 63))
                                    : ((long)row * N + col);
                C[idx] = f2bf((acc[i][j][r] + bj) * oscale);
            }
        }
    }
}

// ---------------------------------------------------------------------------
__global__ __launch_bounds__(256) void gemm_v_bf16(
    const unsigned short* __restrict__ A, const unsigned short* __restrict__ Bt,
    float* __restrict__ C)
{
    __shared__ unsigned short As[128][72];
    __shared__ unsigned short Bs[64][72];

    const int gid = blockIdx.x;
    const int xcd = gid & 7, ii = gid >> 3;          // ii: 0..31
    const int row0 = (xcd * 8 + (ii >> 2)) * 128;
    const int kbeg = (ii & 3) * 256;

    const int tid  = threadIdx.x;
    const int w = tid >> 6, L = tid & 63;
    const int ml = L & 15, q8 = (L >> 4) * 8, q4 = (L >> 4) * 4;
    const int ar = tid >> 3, ac = (tid & 7) * 8;
    const int br = tid >> 2, bc = (tid & 3) * 16;

    f32x4 acc[2][4];
#pragma unroll
    for (int i = 0; i < 2; ++i)
#pragma unroll
        for (int j = 0; j < 4; ++j) acc[i][j] = (f32x4){0.f, 0.f, 0.f, 0.f};

    for (int k0 = kbeg; k0 < kbeg + 256; k0 += 64) {
        __syncthreads();
#pragma unroll
        for (int rr = 0; rr < 128; rr += 32)
            *(float4*)&As[ar + rr][ac] = *(const float4*)&A[(long)(row0 + ar + rr) * HIDc + k0 + ac];
        *(float4*)&Bs[br][bc]     = *(const float4*)&Bt[(long)br * HIDc + k0 + bc];
        *(float4*)&Bs[br][bc + 8] = *(const float4*)&Bt[(long)br * HIDc + k0 + bc + 8];
        __syncthreads();
#pragma unroll
        for (int kk = 0; kk < 64; kk += 32) {
            bf16x8 a[2], b[4];
#pragma unroll
            for (int i = 0; i < 2; ++i) a[i] = *(bf16x8*)&As[w * 32 + i * 16 + ml][kk + q8];
#pragma unroll
            for (int j = 0; j < 4; ++j) b[j] = *(bf16x8*)&Bs[j * 16 + ml][kk + q8];
#pragma unroll
            for (int i = 0; i < 2; ++i)
#pragma unroll
                for (int j = 0; j < 4; ++j)
                    acc[i][j] = __builtin_amdgcn_mfma_f32_16x16x32_bf16(a[i], b[j], acc[i][j], 0, 0, 0);
        }
    }

#pragma unroll
    for (int i = 0; i < 2; ++i)
#pragma unroll
        for (int j = 0; j < 4; ++j)
#pragma unroll
            for (int r = 0; r < 4; ++r)
                atomicAdd(&C[(long)(row0 + w * 32 + i * 16 + q4 + r) * 64 + j * 16 + ml], acc[i][j][r]);
}

// ---------------------------------------------------------------------------
// Attention pass 1: softmax denominators (head-major). Round-13: ITERATION
// MERGING -- two 64-row K-tiles staged per barrier pair (Ks has 128 rows),
// halving the iteration count 32 -> 16. The r11 ablation + r12 depth-2 null
// leave one model standing: time = iterations x fixed exposed latency, so
// halving iterations at constant work is the direct test.
// ---------------------------------------------------------------------------
__global__ __launch_bounds__(256) void attn_denom(
    const unsigned short* __restrict__ qb, const unsigned short* __restrict__ kb,
    float* __restrict__ linv)
{
    const int gid = blockIdx.x;
    const int xcd = gid & 7, ii = gid >> 3;   // ii: 0..127
    const int bh  = xcd * 8 + (ii >> 4);      // 0..63
    const int qt  = ii & 15;
    const int b   = bh >> 4, h = bh & 15;

    __shared__ unsigned short Qs[128][72];
    __shared__ unsigned short Ks[128][72];    // two 64-row K-tiles per iter

    const int tid = threadIdx.x;
    const int w = tid >> 6, L = tid & 63;
    const int ml = L & 15, q8 = (L >> 4) * 8, q4 = (L >> 4) * 4;
    const int ar = tid >> 3, ac = (tid & 7) * 8;
    const int kr = tid >> 2, kc = (tid & 3) * 16;

    const long hb = (long)h * BTc + b * Tt;   // head-major row base

    // Stage 128-row Q slice once (contiguous 16 KB).
#pragma unroll
    for (int rr = 0; rr < 128; rr += 32)
        *(float4*)&Qs[ar + rr][ac] =
            *(const float4*)&qb[(hb + qt * 128 + ar + rr) * HSc + ac];

    const unsigned short* kbase = kb + (hb + kr) * HSc + kc;

    // Prefetch pair 0 (tiles 0 and 1).
    float4 a0 = *(const float4*)kbase;
    float4 a1 = *(const float4*)(kbase + 8);
    float4 b0 = *(const float4*)(kbase + (long)64 * HSc);
    float4 b1 = *(const float4*)(kbase + (long)64 * HSc + 8);

    float lacc[2][4] = {};

    for (int kt = 0; kt < Tt / 64; kt += 2) {
        // Stage both tiles, then prefetch the next pair.
        *(float4*)&Ks[kr][kc]          = a0;
        *(float4*)&Ks[kr][kc + 8]      = a1;
        *(float4*)&Ks[kr + 64][kc]     = b0;
        *(float4*)&Ks[kr + 64][kc + 8] = b1;
        if (kt + 2 < Tt / 64) {
            const unsigned short* sA = kbase + (long)(kt + 2) * 64 * HSc;
            const unsigned short* sB = kbase + (long)(kt + 3) * 64 * HSc;
            a0 = *(const float4*)sA;
            a1 = *(const float4*)(sA + 8);
            b0 = *(const float4*)sB;
            b1 = *(const float4*)(sB + 8);
        }
        bar_lgkm();   // Ks pair (and Qs, first iter) visible

        f32x4 acc[2][8];
#pragma unroll
        for (int i = 0; i < 2; ++i)
#pragma unroll
            for (int j = 0; j < 8; ++j) acc[i][j] = (f32x4){0.f, 0.f, 0.f, 0.f};
#pragma unroll
        for (int kk = 0; kk < 64; kk += 32) {
            bf16x8 a[2], bfr[8];
#pragma unroll
            for (int i = 0; i < 2; ++i) a[i] = *(bf16x8*)&Qs[w * 32 + i * 16 + ml][kk + q8];
#pragma unroll
            for (int j = 0; j < 8; ++j) bfr[j] = *(bf16x8*)&Ks[j * 16 + ml][kk + q8];
#pragma unroll
            for (int i = 0; i < 2; ++i)
#pragma unroll
                for (int j = 0; j < 8; ++j)
                    acc[i][j] = __builtin_amdgcn_mfma_f32_16x16x32_bf16(a[i], bfr[j], acc[i][j], 0, 0, 0);
        }
#pragma unroll
        for (int i = 0; i < 2; ++i)
#pragma unroll
            for (int j = 0; j < 8; ++j)
#pragma unroll
                for (int r = 0; r < 4; ++r)
                    lacc[i][r] += fexp2(acc[i][j][r]);
        bar_lgkm();   // all ds_reads done before next overwrite
    }

#pragma unroll
    for (int i = 0; i < 2; ++i)
#pragma unroll
        for (int r = 0; r < 4; ++r) {
            float v = lacc[i][r];
            v += __shfl_xor(v, 1, 16);
            v += __shfl_xor(v, 2, 16);
            v += __shfl_xor(v, 4, 16);
            v += __shfl_xor(v, 8, 16);
            if (ml == 0)
                linv[((long)(b * NHc + h)) * Tt + qt * 128 + w * 32 + i * 16 + q4 + r] =
                    1.0f / (v * (float)NHc);
        }
}

// ---------------------------------------------------------------------------
// Attention pass 2 (FUSED 128x128, 512 threads / 8 waves, head-major).
// Round-13: ITERATION MERGING -- two heads per barrier pair (banks A/B in
// LDS), halving the head-loop iteration count 16 -> 8 at constant total
// work. LDS 80 KB -> 2 blocks/CU (16 waves). Depth-1 pair prefetch (depth-2
// proven harmful in r12).
// ---------------------------------------------------------------------------
__global__ __launch_bounds__(512) void attn_avg_w(
    const unsigned short* __restrict__ qb, const unsigned short* __restrict__ kb,
    const float* __restrict__ linv, const float* __restrict__ v,
    float* __restrict__ attn, float* __restrict__ o1)
{
    const int gid = blockIdx.x;
    const int xcd = gid & 7, ii = gid >> 3;   // ii: 0..127
    const int b = xcd >> 1, qhalf = xcd & 1;
    const int t = ii >> 4, u = ii & 15;
    const int qt  = qhalf * 8 + (t & 1) * 4 + (u >> 2);   // 0..15
    const int ktg = (t >> 1) * 4 + (u & 3);               // 0..15

    // LDS: phase1 {QsA,KsA,QsB,KsB 4x18432 = 73728, invsAll 8192} = 81920 B
    //      phase2 {Ps 128x136 @0 (34816), Vst 64x136 @34816 (17408)}
    __shared__ __align__(16) unsigned char smem[81920];
    unsigned short (*QsA)[72]  = (unsigned short(*)[72])smem;
    unsigned short (*KsA)[72]  = (unsigned short(*)[72])(smem + 18432);
    unsigned short (*QsB)[72]  = (unsigned short(*)[72])(smem + 36864);
    unsigned short (*KsB)[72]  = (unsigned short(*)[72])(smem + 55296);
    float (*invsAll)[128]      = (float(*)[128])(smem + 73728);
    unsigned short (*Ps)[136]  = (unsigned short(*)[136])smem;
    unsigned short (*Vst)[136] = (unsigned short(*)[136])(smem + 34816);

    const int tid = threadIdx.x;
    const int w = tid >> 6, L = tid & 63;
    const int ml = L & 15, q8 = (L >> 4) * 8, q4 = (L >> 4) * 4;
    const int wq = (w >> 2) * 64;
    const int wk = (w & 3) * 32;
    const int sr = tid >> 2, sc = (tid & 3) * 16;

    // Stage all 16 heads' 1/(l*NH) once.
    {
        const int hh = tid >> 5, r4 = (tid & 31) * 4;
        *(float4*)&invsAll[hh][r4] =
            *(const float4*)&linv[((long)(b * NHc + hh)) * Tt + qt * 128 + r4];
    }

    const unsigned short* qbase = qb + ((long)(b * Tt + qt * 128 + sr)) * HSc + sc;
    const unsigned short* kbase = kb + ((long)(b * Tt + ktg * 128 + sr)) * HSc + sc;
    const long hstep = (long)BTc * HSc;   // head stride (head-major layout)

    // Prefetch heads 0 and 1.
    float4 qA[2], kA[2], qB[2], kB[2];
#pragma unroll
    for (int c = 0; c < 2; ++c) {
        qA[c] = *(const float4*)(qbase + c * 8);
        kA[c] = *(const float4*)(kbase + c * 8);
        qB[c] = *(const float4*)(qbase + hstep + c * 8);
        kB[c] = *(const float4*)(kbase + hstep + c * 8);
    }

    float pacc[4][2][4] = {};

#define AVG_COMPUTE(QS, KS, H)                                                 \
    {                                                                          \
        f32x4 acc[4][2];                                                       \
        _Pragma("unroll")                                                      \
        for (int i = 0; i < 4; ++i)                                            \
            _Pragma("unroll")                                                  \
            for (int j = 0; j < 2; ++j) acc[i][j] = (f32x4){0.f,0.f,0.f,0.f};  \
        _Pragma("unroll")                                                      \
        for (int kk = 0; kk < 64; kk += 32) {                                  \
            bf16x8 a[4], bfr[2];                                               \
            _Pragma("unroll")                                                  \
            for (int i = 0; i < 4; ++i)                                        \
                a[i] = *(bf16x8*)&QS[wq + i * 16 + ml][kk + q8];               \
            _Pragma("unroll")                                                  \
            for (int j = 0; j < 2; ++j)                                        \
                bfr[j] = *(bf16x8*)&KS[wk + j * 16 + ml][kk + q8];             \
            _Pragma("unroll")                                                  \
            for (int i = 0; i < 4; ++i)                                        \
                _Pragma("unroll")                                              \
                for (int j = 0; j < 2; ++j)                                    \
                    acc[i][j] = __builtin_amdgcn_mfma_f32_16x16x32_bf16(       \
                        a[i], bfr[j], acc[i][j], 0, 0, 0);                     \
        }                                                                      \
        float ivr[4][4];                                                       \
        _Pragma("unroll")                                                      \
        for (int i = 0; i < 4; ++i)                                            \
            *(float4*)&ivr[i][0] = *(const float4*)&invsAll[H][wq + i*16 + q4];\
        _Pragma("unroll")                                                      \
        for (int i = 0; i < 4; ++i)                                            \
            _Pragma("unroll")                                                  \
            for (int j = 0; j < 2; ++j)                                        \
                _Pragma("unroll")                                              \
                for (int r = 0; r < 4; ++r)                                    \
                    pacc[i][j][r] += fexp2(acc[i][j][r]) * ivr[i][r];          \
    }

    for (int h = 0; h < NHc; h += 2) {
        // Stage both heads from regs, then prefetch the next pair.
#pragma unroll
        for (int c = 0; c < 2; ++c) {
            *(float4*)&QsA[sr][sc + c * 8] = qA[c];
            *(float4*)&KsA[sr][sc + c * 8] = kA[c];
            *(float4*)&QsB[sr][sc + c * 8] = qB[c];
            *(float4*)&KsB[sr][sc + c * 8] = kB[c];
        }
        if (h + 2 < NHc) {
            const unsigned short* sqA = qbase + (h + 2) * hstep;
            const unsigned short* skA = kbase + (h + 2) * hstep;
            const unsigned short* sqB = qbase + (h + 3) * hstep;
            const unsigned short* skB = kbase + (h + 3) * hstep;
#pragma unroll
            for (int c = 0; c < 2; ++c) {
                qA[c] = *(const float4*)(sqA + c * 8);
                kA[c] = *(const float4*)(skA + c * 8);
                qB[c] = *(const float4*)(sqB + c * 8);
                kB[c] = *(const float4*)(skB + c * 8);
            }
        }
        bar_lgkm();   // both banks (and invsAll, first iter) visible

        AVG_COMPUTE(QsA, KsA, h);
        AVG_COMPUTE(QsB, KsB, h + 1);

        bar_lgkm();   // reads done before next pair's writes
    }
#undef AVG_COMPUTE
    // (last bar_lgkm: all phase-1 LDS reads complete -> overlay safe)

    // Epilogue: write attn (fp32) + Ps (bf16) for the PV step.
#pragma unroll
    for (int i = 0; i < 4; ++i)
#pragma unroll
        for (int j = 0; j < 2; ++j)
#pragma unroll
            for (int r = 0; r < 4; ++r) {
                const int qrow = wq + i * 16 + q4 + r;
                const int col  = wk + j * 16 + ml;
                attn[((long)(b * Tt + qt * 128 + qrow)) * Tt + ktg * 128 + col] = pacc[i][j][r];
                Ps[qrow][col] = f2bf(pacc[i][j][r]);
            }
    // Stage V^T: Vst[d][k] over k-range of this tile.
#pragma unroll
    for (int e = tid; e < 8192; e += 512) {
        const int r = e >> 6, d = e & 63;
        Vst[d][r] = f2bf(v[((long)(b * Tt + ktg * 128 + r)) * 64 + d]);
    }
    bar_lgkm();

    // U(128x64) = P(128x128) @ V(128x64); wave: 32 q-rows x 32 d-cols.
    const int pq = (w >> 1) * 32, wd = (w & 1) * 32;
    f32x4 uacc[2][2];
#pragma unroll
    for (int i = 0; i < 2; ++i)
#pragma unroll
        for (int j = 0; j < 2; ++j) uacc[i][j] = (f32x4){0.f, 0.f, 0.f, 0.f};
#pragma unroll
    for (int kk = 0; kk < 128; kk += 32) {
        bf16x8 a2[2], bvv[2];
#pragma unroll
        for (int i = 0; i < 2; ++i) a2[i]  = *(bf16x8*)&Ps[pq + i * 16 + ml][kk + q8];
#pragma unroll
        for (int j = 0; j < 2; ++j) bvv[j] = *(bf16x8*)&Vst[wd + j * 16 + ml][kk + q8];
#pragma unroll
        for (int i = 0; i < 2; ++i)
#pragma unroll
            for (int j = 0; j < 2; ++j)
                uacc[i][j] = __builtin_amdgcn_mfma_f32_16x16x32_bf16(a2[i], bvv[j], uacc[i][j], 0, 0, 0);
    }
#pragma unroll
    for (int i = 0; i < 2; ++i)
#pragma unroll
        for (int j = 0; j < 2; ++j)
#pragma unroll
            for (int r = 0; r < 4; ++r)
                atomicAdd(&o1[((long)(b * Tt + qt * 128 + pq + i * 16 + q4 + r)) * 64 + wd + j * 16 + ml],
                          uacc[i][j][r]);
}

// ---------------------------------------------------------------------------
extern "C" void kernel_launch(void* const* d_in, const int* in_sizes, int n_in,
                              void* d_out, int out_size, void* d_ws, size_t ws_size,
                              hipStream_t stream)
{
    const float* x  = (const float*)d_in[0];
    const float* Wq = (const float*)d_in[1];
    const float* bq = (const float*)d_in[2];
    const float* Wk = (const float*)d_in[3];
    const float* bk = (const float*)d_in[4];
    const float* Wv = (const float*)d_in[5];
    const float* bv = (const float*)d_in[6];
    const float* Wo = (const float*)d_in[7];
    const float* bo = (const float*)d_in[8];

    float* out  = (float*)d_out;                    // B*T*HID
    float* attn = out + (long)BTc * HIDc;           // B*T*T

    // workspace: xb | Wqt | Wkt | Wvt | qb | kb | v | linv | o1  (~59 MB)
    unsigned short* xb  = (unsigned short*)d_ws;
    unsigned short* Wqt = xb  + (long)BTc * HIDc;
    unsigned short* Wkt = Wqt + (long)HIDc * HIDc;
    unsigned short* Wvt = Wkt + (long)HIDc * HIDc;
    unsigned short* qb  = Wvt + (long)HSc * HIDc;   // head-major (NH, B*T, HS)
    unsigned short* kb  = qb  + (long)BTc * HIDc;   // head-major (NH, B*T, HS)
    float* v    = (float*)(kb + (long)BTc * HIDc);
    float* linv = v    + (long)BTc * HSc;
    float* o1   = linv + (long)Bc * NHc * Tt;

    dim3 blk(256);

    // prep
    cast_bf16<<<dim3((BTc * HIDc) / 1024), blk, 0, stream>>>(x, xb, (long)BTc * HIDc);
    transpose_cast<<<dim3(32, 32), blk, 0, stream>>>(Wq, Wqt, HIDc, HIDc);
    transpose_cast<<<dim3(32, 32), blk, 0, stream>>>(Wk, Wkt, HIDc, HIDc);
    transpose_cast<<<dim3(32, 2),  blk, 0, stream>>>(Wv, Wvt, HIDc, HSc);
    init_bias64<<<dim3((BTc * HSc) / 256), blk, 0, stream>>>(v,  bv,      (long)BTc * HSc);
    init_bias64<<<dim3((BTc * HSc) / 256), blk, 0, stream>>>(o1, nullptr, (long)BTc * HSc);

    // Q/K projections (bf16 MFMA, XCD-swizzled; head-major output layout).
    gemm_bt_bf16<<<dim3(512), blk, 0, stream>>>(xb, Wqt, bq, qb, BTc, HIDc, HIDc, QSCALE, 1);
    gemm_bt_bf16<<<dim3(512), blk, 0, stream>>>(xb, Wkt, bk, kb, BTc, HIDc, HIDc, 1.0f, 1);

    // V projection
    gemm_v_bf16<<<dim3(256), blk, 0, stream>>>(xb, Wvt, v);

    // pass 1: softmax denominators (2 K-tiles per barrier pair: 16 iters)
    attn_denom<<<dim3(1024), blk, 0, stream>>>(qb, kb, linv);

    // pass 2 (fused 128x128, 8 waves, 2 heads per barrier pair: 8 iters)
    attn_avg_w<<<dim3(1024), dim3(512), 0, stream>>>(qb, kb, linv, v, attn, o1);

    // out = o1 @ Wo + bo
    gemm_f32<<<dim3(HIDc / 64, BTc / 64), blk, 0, stream>>>(o1, Wo, bo, out, BTc, HIDc, HSc);
}

// Round 14
// 449.320 us; speedup vs baseline: 1.0780x; 1.0780x over previous
//
#include <hip/hip_runtime.h>
#include <math.h>

// Problem constants (fixed by the reference)
#define Bc   4
#define Tt   2048
#define HIDc 1024
#define NHc  16
#define HSc  64
#define BTc  (Bc * Tt)          // 8192
#define QSCALE 0.18033688011112042f   // 0.125 * log2(e): folded into q so exp(s/8)=2^acc

typedef __attribute__((ext_vector_type(8))) short bf16x8;   // 8 bf16 = 4 VGPRs
typedef __attribute__((ext_vector_type(4))) float f32x4;

__device__ __forceinline__ unsigned short f2bf(float f) {
    unsigned u = __float_as_uint(f);
    u = u + 0x7FFFu + ((u >> 16) & 1u);   // round-to-nearest-even
    return (unsigned short)(u >> 16);
}

__device__ __forceinline__ float fexp2(float x) {
#if __has_builtin(__builtin_amdgcn_exp2f)
    return __builtin_amdgcn_exp2f(x);
#else
    float r; asm("v_exp_f32 %0, %1" : "=v"(r) : "v"(x)); return r;
#endif
}

// ---------------------------------------------------------------------------
// fp32 GEMM (Wo epilogue): C = A @ B + bias, 64x64 tile.
// ---------------------------------------------------------------------------
__global__ __launch_bounds__(256) void gemm_f32(
    const float* __restrict__ A, const float* __restrict__ Bm,
    const float* __restrict__ bias, float* __restrict__ C,
    int M, int N, int K)
{
    __shared__ float As[16][64];
    __shared__ float Bs[16][64];

    const int tid  = threadIdx.x;
    const int tx   = tid & 15;
    const int ty   = tid >> 4;
    const int row0 = blockIdx.y * 64;
    const int col0 = blockIdx.x * 64;

    const int la_r = tid >> 2;
    const int la_c = (tid & 3) << 2;
    const int lb_r = tid >> 4;
    const int lb_c = (tid & 15) << 2;

    float acc[4][4] = {};

    for (int k0 = 0; k0 < K; k0 += 16) {
        float4 av = *(const float4*)&A[(long)(row0 + la_r) * K + k0 + la_c];
        float4 bv = *(const float4*)&Bm[(long)(k0 + lb_r) * N + col0 + lb_c];
        __syncthreads();
        As[la_c + 0][la_r] = av.x;
        As[la_c + 1][la_r] = av.y;
        As[la_c + 2][la_r] = av.z;
        As[la_c + 3][la_r] = av.w;
        *(float4*)&Bs[lb_r][lb_c] = bv;
        __syncthreads();
#pragma unroll
        for (int kk = 0; kk < 16; ++kk) {
            float4 a = *(float4*)&As[kk][ty << 2];
            float4 b = *(float4*)&Bs[kk][tx << 2];
            float ar[4] = {a.x, a.y, a.z, a.w};
            float br[4] = {b.x, b.y, b.z, b.w};
#pragma unroll
            for (int i = 0; i < 4; ++i)
#pragma unroll
                for (int j = 0; j < 4; ++j)
                    acc[i][j] = fmaf(ar[i], br[j], acc[i][j]);
        }
    }

    float4 bvv = make_float4(0.f, 0.f, 0.f, 0.f);
    if (bias) bvv = *(const float4*)&bias[col0 + (tx << 2)];
#pragma unroll
    for (int i = 0; i < 4; ++i) {
        int m = row0 + (ty << 2) + i;
        float4 o;
        o.x = acc[i][0] + bvv.x;
        o.y = acc[i][1] + bvv.y;
        o.z = acc[i][2] + bvv.z;
        o.w = acc[i][3] + bvv.w;
        *(float4*)&C[(long)m * N + col0 + (tx << 2)] = o;
    }
}

// ---------------------------------------------------------------------------
// Init C(rows,64) with broadcast bias (or zero).
// ---------------------------------------------------------------------------
__global__ __launch_bounds__(256) void init_bias64(
    float* __restrict__ C, const float* __restrict__ bias, long n)
{
    long idx = (long)blockIdx.x * 256 + threadIdx.x;
    if (idx < n) C[idx] = bias ? bias[idx & 63] : 0.f;
}

// ---------------------------------------------------------------------------
// Prep: cast fp32 -> bf16
// ---------------------------------------------------------------------------
__global__ __launch_bounds__(256) void cast_bf16(
    const float* __restrict__ src, unsigned short* __restrict__ dst, long n)
{
    long i = ((long)blockIdx.x * 256 + threadIdx.x) * 4;
    if (i >= n) return;
    float4 v = *(const float4*)&src[i];
    ushort4 o;
    o.x = f2bf(v.x); o.y = f2bf(v.y); o.z = f2bf(v.z); o.w = f2bf(v.w);
    *(ushort4*)&dst[i] = o;
}

// ---------------------------------------------------------------------------
// Prep: transpose + cast: Wt[n][k] = (bf16) W[k][n].  W is RxC, Wt is CxR.
// grid: (R/32, C/32)
// ---------------------------------------------------------------------------
__global__ __launch_bounds__(256) void transpose_cast(
    const float* __restrict__ W, unsigned short* __restrict__ Wt, int R, int C)
{
    __shared__ float t[32][33];
    const int k0 = blockIdx.x * 32, n0 = blockIdx.y * 32;
    const int c = threadIdx.x & 31, r = threadIdx.x >> 5;  // r: 0..7
#pragma unroll
    for (int rr = r; rr < 32; rr += 8)
        t[rr][c] = W[(long)(k0 + rr) * C + n0 + c];
    __syncthreads();
#pragma unroll
    for (int rr = r; rr < 32; rr += 8)
        Wt[(long)(n0 + rr) * R + k0 + c] = f2bf(t[c][rr]);
}

// ---------------------------------------------------------------------------
// bf16 MFMA GEMM, B^T input: C(M,N) bf16 = ((A @ Bt^T) + bias) * oscale
// 128x128 tile, BK=64, 256 threads (4 waves, 64x64 quadrant each).
// 1-D grid 512, XCD-swizzled (halved FETCH in round 4).
// ---------------------------------------------------------------------------
__global__ __launch_bounds__(256) void gemm_bt_bf16(
    const unsigned short* __restrict__ A, const unsigned short* __restrict__ Bt,
    const float* __restrict__ bias, unsigned short* __restrict__ C,
    int M, int N, int K, float oscale)
{
    __shared__ unsigned short As[128][72];
    __shared__ unsigned short Bs[128][72];

    const int gid = blockIdx.x;
    const int xcd = gid & 7, ii = gid >> 3;          // ii: 0..63
    const int row0 = (xcd * 8 + (ii >> 3)) * 128;    // row-tile 0..63
    const int col0 = (ii & 7) * 128;                 // col-tile 0..7

    const int tid  = threadIdx.x;
    const int w  = tid >> 6, L = tid & 63;
    const int wm = (w & 1) * 64, wn = (w >> 1) * 64;
    const int lr = tid >> 3;          // staging row (0..31, +32 steps)
    const int lc = (tid & 7) * 8;     // staging dim chunk (8 bf16 = 16 B)
    const int ml = L & 15, q8 = (L >> 4) * 8, q4 = (L >> 4) * 4;

    f32x4 acc[4][4];
#pragma unroll
    for (int i = 0; i < 4; ++i)
#pragma unroll
        for (int j = 0; j < 4; ++j)
            acc[i][j] = (f32x4){0.f, 0.f, 0.f, 0.f};

    for (int k0 = 0; k0 < K; k0 += 64) {
        __syncthreads();
#pragma unroll
        for (int rr = 0; rr < 128; rr += 32) {
            *(float4*)&As[lr + rr][lc] = *(const float4*)&A[(long)(row0 + lr + rr) * K + k0 + lc];
            *(float4*)&Bs[lr + rr][lc] = *(const float4*)&Bt[(long)(col0 + lr + rr) * K + k0 + lc];
        }
        __syncthreads();
#pragma unroll
        for (int kk = 0; kk < 64; kk += 32) {
            bf16x8 a[4], b[4];
#pragma unroll
            for (int i = 0; i < 4; ++i) a[i] = *(bf16x8*)&As[wm + i * 16 + ml][kk + q8];
#pragma unroll
            for (int j = 0; j < 4; ++j) b[j] = *(bf16x8*)&Bs[wn + j * 16 + ml][kk + q8];
#pragma unroll
            for (int i = 0; i < 4; ++i)
#pragma unroll
                for (int j = 0; j < 4; ++j)
                    acc[i][j] = __builtin_amdgcn_mfma_f32_16x16x32_bf16(a[i], b[j], acc[i][j], 0, 0, 0);
        }
    }

#pragma unroll
    for (int j = 0; j < 4; ++j) {
        const int col = col0 + wn + j * 16 + ml;
        const float bj = bias ? bias[col] : 0.f;
#pragma unroll
        for (int i = 0; i < 4; ++i) {
#pragma unroll
            for (int r = 0; r < 4; ++r) {
                const int row = row0 + wm + i * 16 + q4 + r;
                C[(long)row * N + col] = f2bf((acc[i][j][r] + bj) * oscale);
            }
        }
    }
}

// ---------------------------------------------------------------------------
// V projection, bf16 MFMA split-K: C(8192,64) fp32 += xb(8192,1024)[kchunk] @ Wvt^T
// 1-D grid 256, XCD-swizzled. Caller pre-inits C with bias.
// ---------------------------------------------------------------------------
__global__ __launch_bounds__(256) void gemm_v_bf16(
    const unsigned short* __restrict__ A, const unsigned short* __restrict__ Bt,
    float* __restrict__ C)
{
    __shared__ unsigned short As[128][72];
    __shared__ unsigned short Bs[64][72];

    const int gid = blockIdx.x;
    const int xcd = gid & 7, ii = gid >> 3;          // ii: 0..31
    const int row0 = (xcd * 8 + (ii >> 2)) * 128;    // row-tile 0..63
    const int kbeg = (ii & 3) * 256;                 // k-chunk 0..3

    const int tid  = threadIdx.x;
    const int w = tid >> 6, L = tid & 63;
    const int ml = L & 15, q8 = (L >> 4) * 8, q4 = (L >> 4) * 4;
    const int ar = tid >> 3, ac = (tid & 7) * 8;
    const int br = tid >> 2, bc = (tid & 3) * 16;

    f32x4 acc[2][4];
#pragma unroll
    for (int i = 0; i < 2; ++i)
#pragma unroll
        for (int j = 0; j < 4; ++j) acc[i][j] = (f32x4){0.f, 0.f, 0.f, 0.f};

    for (int k0 = kbeg; k0 < kbeg + 256; k0 += 64) {
        __syncthreads();
#pragma unroll
        for (int rr = 0; rr < 128; rr += 32)
            *(float4*)&As[ar + rr][ac] = *(const float4*)&A[(long)(row0 + ar + rr) * HIDc + k0 + ac];
        *(float4*)&Bs[br][bc]     = *(const float4*)&Bt[(long)br * HIDc + k0 + bc];
        *(float4*)&Bs[br][bc + 8] = *(const float4*)&Bt[(long)br * HIDc + k0 + bc + 8];
        __syncthreads();
#pragma unroll
        for (int kk = 0; kk < 64; kk += 32) {
            bf16x8 a[2], b[4];
#pragma unroll
            for (int i = 0; i < 2; ++i) a[i] = *(bf16x8*)&As[w * 32 + i * 16 + ml][kk + q8];
#pragma unroll
            for (int j = 0; j < 4; ++j) b[j] = *(bf16x8*)&Bs[j * 16 + ml][kk + q8];
#pragma unroll
            for (int i = 0; i < 2; ++i)
#pragma unroll
                for (int j = 0; j < 4; ++j)
                    acc[i][j] = __builtin_amdgcn_mfma_f32_16x16x32_bf16(a[i], b[j], acc[i][j], 0, 0, 0);
        }
    }

#pragma unroll
    for (int i = 0; i < 2; ++i)
#pragma unroll
        for (int j = 0; j < 4; ++j)
#pragma unroll
            for (int r = 0; r < 4; ++r)
                atomicAdd(&C[(long)(row0 + w * 32 + i * 16 + q4 + r) * 64 + j * 16 + ml], acc[i][j][r]);
}

// ---------------------------------------------------------------------------
// Attention pass 1: softmax denominators. q pre-scaled by QSCALE so
// exp(s/8) = 2^(q'.k). 1-D grid 1024, XCD-swizzled.
// ---------------------------------------------------------------------------
__global__ __launch_bounds__(256) void attn_denom(
    const unsigned short* __restrict__ qb, const unsigned short* __restrict__ kb,
    float* __restrict__ linv)
{
    const int gid = blockIdx.x;
    const int xcd = gid & 7, ii = gid >> 3;   // ii: 0..127
    const int bh  = xcd * 8 + (ii >> 4);      // 0..63
    const int qt  = ii & 15;
    const int b   = bh >> 4, h = bh & 15;

    __shared__ unsigned short Qs[128][72];
    __shared__ unsigned short Ks[64][72];

    const int tid = threadIdx.x;
    const int w = tid >> 6, L = tid & 63;
    const int ml = L & 15, q8 = (L >> 4) * 8, q4 = (L >> 4) * 4;
    const int ar = tid >> 3, ac = (tid & 7) * 8;
    const int kr = tid >> 2, kc = (tid & 3) * 16;

    // Stage 128-row Q slice once.
#pragma unroll
    for (int rr = 0; rr < 128; rr += 32)
        *(float4*)&Qs[ar + rr][ac] =
            *(const float4*)&qb[(long)(b * Tt + qt * 128 + ar + rr) * HIDc + h * HSc + ac];

    const unsigned short* kbase = kb + ((long)(b * Tt + kr) * HIDc + h * HSc + kc);
    float4 v0 = *(const float4*)kbase;
    float4 v1 = *(const float4*)(kbase + 8);

    float lacc[2][4] = {};

    for (int kt = 0; kt < Tt / 64; ++kt) {
        *(float4*)&Ks[kr][kc]     = v0;
        *(float4*)&Ks[kr][kc + 8] = v1;
        if (kt + 1 < Tt / 64) {
            const unsigned short* s = kbase + (long)(kt + 1) * 64 * HIDc;
            v0 = *(const float4*)s;
            v1 = *(const float4*)(s + 8);
        }
        __syncthreads();   // Ks(kt) (and Qs, first iter) visible

        f32x4 acc[2][4];
#pragma unroll
        for (int i = 0; i < 2; ++i)
#pragma unroll
            for (int j = 0; j < 4; ++j) acc[i][j] = (f32x4){0.f, 0.f, 0.f, 0.f};
#pragma unroll
        for (int kk = 0; kk < 64; kk += 32) {
            bf16x8 a[2], bfr[4];
#pragma unroll
            for (int i = 0; i < 2; ++i) a[i] = *(bf16x8*)&Qs[w * 32 + i * 16 + ml][kk + q8];
#pragma unroll
            for (int j = 0; j < 4; ++j) bfr[j] = *(bf16x8*)&Ks[j * 16 + ml][kk + q8];
#pragma unroll
            for (int i = 0; i < 2; ++i)
#pragma unroll
                for (int j = 0; j < 4; ++j)
                    acc[i][j] = __builtin_amdgcn_mfma_f32_16x16x32_bf16(a[i], bfr[j], acc[i][j], 0, 0, 0);
        }
#pragma unroll
        for (int i = 0; i < 2; ++i)
#pragma unroll
            for (int j = 0; j < 4; ++j)
#pragma unroll
                for (int r = 0; r < 4; ++r)
                    lacc[i][r] += fexp2(acc[i][j][r]);
        __syncthreads();   // all reads done before next Ks write
    }

#pragma unroll
    for (int i = 0; i < 2; ++i)
#pragma unroll
        for (int r = 0; r < 4; ++r) {
            float v = lacc[i][r];
            v += __shfl_xor(v, 1, 16);
            v += __shfl_xor(v, 2, 16);
            v += __shfl_xor(v, 4, 16);
            v += __shfl_xor(v, 8, 16);
            if (ml == 0)
                linv[((long)(b * NHc + h)) * Tt + qt * 128 + w * 32 + i * 16 + q4 + r] =
                    1.0f / (v * (float)NHc);
        }
}

// ---------------------------------------------------------------------------
// Attention pass 2 (FUSED, 128x128 tile, 512 threads / 8 waves) -- the
// round-6 configuration, the best measured this session (442.0 us total).
// 13 falsification attempts on the ~176 us attention invariant (store shape,
// atomics, traffic, XCD locality, fusion, tile size, occupancy, barriers,
// barrier drain, layout, prefetch depth, iteration count) all nulled or
// regressed; consolidating at the measured optimum.
// QK^T: waves 2(q)x4(k); PV: waves 4(q)x2(d). Grid 1024, XCD-swizzled.
// ---------------------------------------------------------------------------
__global__ __launch_bounds__(512) void attn_avg_w(
    const unsigned short* __restrict__ qb, const unsigned short* __restrict__ kb,
    const float* __restrict__ linv, const float* __restrict__ v,
    float* __restrict__ attn, float* __restrict__ o1)
{
    const int gid = blockIdx.x;
    const int xcd = gid & 7, ii = gid >> 3;   // ii: 0..127
    const int b = xcd >> 1, qhalf = xcd & 1;
    const int t = ii >> 4, u = ii & 15;       // t: 0..7 (2q x 4k supertiles)
    const int qt  = qhalf * 8 + (t & 1) * 4 + (u >> 2);   // 0..15
    const int ktg = (t >> 1) * 4 + (u & 3);               // 0..15

    // LDS overlay: phase1 {Qs 128x72, Ks 128x72, invsAll 16x128} (45056 B)
    //              phase2 {Ps 128x136 @0, Vst 64x136 @34816}     (52224 B)
    __shared__ __align__(16) unsigned char smem[52224];
    unsigned short (*Qs)[72]   = (unsigned short(*)[72])smem;             // 18432 B
    unsigned short (*Ks)[72]   = (unsigned short(*)[72])(smem + 18432);   // 18432 B
    float (*invsAll)[128]      = (float(*)[128])(smem + 36864);           // 8192 B
    unsigned short (*Ps)[136]  = (unsigned short(*)[136])smem;            // 34816 B
    unsigned short (*Vst)[136] = (unsigned short(*)[136])(smem + 34816);  // 17408 B

    const int tid = threadIdx.x;
    const int w = tid >> 6, L = tid & 63;
    const int ml = L & 15, q8 = (L >> 4) * 8, q4 = (L >> 4) * 4;
    const int wq = (w >> 2) * 64;     // wave q-offset, scores (2 strips of 64)
    const int wk = (w & 3) * 32;      // wave k-offset, scores (4 strips of 32)
    const int sr = tid >> 2, sc = (tid & 3) * 16;   // staging: row 0..127, 16-col chunk

    // Stage all 16 heads' 1/(l*NH) once: thread t -> head t>>5, rows (t&31)*4..+3
    {
        const int hh = tid >> 5, r4 = (tid & 31) * 4;
        *(float4*)&invsAll[hh][r4] =
            *(const float4*)&linv[((long)(b * NHc + hh)) * Tt + qt * 128 + r4];
    }

    const unsigned short* qbase = qb + ((long)(b * Tt + qt * 128 + sr) * HIDc + sc);
    const unsigned short* kbase = kb + ((long)(b * Tt + ktg * 128 + sr) * HIDc + sc);

    // Prefetch head 0 into registers (2 float4 Q + 2 float4 K per thread).
    float4 qv[2], kv[2];
#pragma unroll
    for (int c = 0; c < 2; ++c) {
        qv[c] = *(const float4*)(qbase + c * 8);
        kv[c] = *(const float4*)(kbase + c * 8);
    }

    float pacc[4][2][4] = {};

    for (int h = 0; h < NHc; ++h) {
        // Write LDS from regs(h), then issue loads for h+1 (T14: latency
        // hides under this head's MFMA+exp).
#pragma unroll
        for (int c = 0; c < 2; ++c) {
            *(float4*)&Qs[sr][sc + c * 8] = qv[c];
            *(float4*)&Ks[sr][sc + c * 8] = kv[c];
        }
        if (h + 1 < NHc) {
            const unsigned short* sq = qbase + (h + 1) * HSc;
            const unsigned short* sk = kbase + (h + 1) * HSc;
#pragma unroll
            for (int c = 0; c < 2; ++c) {
                qv[c] = *(const float4*)(sq + c * 8);
                kv[c] = *(const float4*)(sk + c * 8);
            }
        }
        __syncthreads();   // LDS(h) visible (first iter also covers invsAll)

        f32x4 acc[4][2];
#pragma unroll
        for (int i = 0; i < 4; ++i)
#pragma unroll
            for (int j = 0; j < 2; ++j) acc[i][j] = (f32x4){0.f, 0.f, 0.f, 0.f};
#pragma unroll
        for (int kk = 0; kk < 64; kk += 32) {
            bf16x8 a[4], bfr[2];
#pragma unroll
            for (int i = 0; i < 4; ++i) a[i]   = *(bf16x8*)&Qs[wq + i * 16 + ml][kk + q8];
#pragma unroll
            for (int j = 0; j < 2; ++j) bfr[j] = *(bf16x8*)&Ks[wk + j * 16 + ml][kk + q8];
#pragma unroll
            for (int i = 0; i < 4; ++i)
#pragma unroll
                for (int j = 0; j < 2; ++j)
                    acc[i][j] = __builtin_amdgcn_mfma_f32_16x16x32_bf16(a[i], bfr[j], acc[i][j], 0, 0, 0);
        }
        float ivr[4][4];
#pragma unroll
        for (int i = 0; i < 4; ++i)
            *(float4*)&ivr[i][0] = *(const float4*)&invsAll[h][wq + i * 16 + q4];
#pragma unroll
        for (int i = 0; i < 4; ++i)
#pragma unroll
            for (int j = 0; j < 2; ++j)
#pragma unroll
                for (int r = 0; r < 4; ++r)
                    pacc[i][j][r] += fexp2(acc[i][j][r]) * ivr[i][r];
        __syncthreads();   // reads of LDS(h) done before next head's write
    }
    // (trailing barrier: all Qs/Ks/invsAll reads complete -> overlay safe)

    // Epilogue: write attn (fp32) + Ps (bf16) for the PV step.
#pragma unroll
    for (int i = 0; i < 4; ++i)
#pragma unroll
        for (int j = 0; j < 2; ++j)
#pragma unroll
            for (int r = 0; r < 4; ++r) {
                const int qrow = wq + i * 16 + q4 + r;
                const int col  = wk + j * 16 + ml;
                attn[((long)(b * Tt + qt * 128 + qrow)) * Tt + ktg * 128 + col] = pacc[i][j][r];
                Ps[qrow][col] = f2bf(pacc[i][j][r]);
            }
    // Stage V^T: Vst[d][k] over k-range of this tile.
#pragma unroll
    for (int e = tid; e < 8192; e += 512) {
        const int r = e >> 6, d = e & 63;
        Vst[d][r] = f2bf(v[((long)(b * Tt + ktg * 128 + r)) * 64 + d]);
    }
    __syncthreads();

    // U(128x64) = P(128x128) @ V(128x64); wave: 32 q-rows x 32 d-cols.
    const int pq = (w >> 1) * 32, wd = (w & 1) * 32;
    f32x4 uacc[2][2];
#pragma unroll
    for (int i = 0; i < 2; ++i)
#pragma unroll
        for (int j = 0; j < 2; ++j) uacc[i][j] = (f32x4){0.f, 0.f, 0.f, 0.f};
#pragma unroll
    for (int kk = 0; kk < 128; kk += 32) {
        bf16x8 a2[2], bvv[2];
#pragma unroll
        for (int i = 0; i < 2; ++i) a2[i]  = *(bf16x8*)&Ps[pq + i * 16 + ml][kk + q8];
#pragma unroll
        for (int j = 0; j < 2; ++j) bvv[j] = *(bf16x8*)&Vst[wd + j * 16 + ml][kk + q8];
#pragma unroll
        for (int i = 0; i < 2; ++i)
#pragma unroll
            for (int j = 0; j < 2; ++j)
                uacc[i][j] = __builtin_amdgcn_mfma_f32_16x16x32_bf16(a2[i], bvv[j], uacc[i][j], 0, 0, 0);
    }
#pragma unroll
    for (int i = 0; i < 2; ++i)
#pragma unroll
        for (int j = 0; j < 2; ++j)
#pragma unroll
            for (int r = 0; r < 4; ++r)
                atomicAdd(&o1[((long)(b * Tt + qt * 128 + pq + i * 16 + q4 + r)) * 64 + wd + j * 16 + ml],
                          uacc[i][j][r]);
}

// ---------------------------------------------------------------------------
extern "C" void kernel_launch(void* const* d_in, const int* in_sizes, int n_in,
                              void* d_out, int out_size, void* d_ws, size_t ws_size,
                              hipStream_t stream)
{
    const float* x  = (const float*)d_in[0];
    const float* Wq = (const float*)d_in[1];
    const float* bq = (const float*)d_in[2];
    const float* Wk = (const float*)d_in[3];
    const float* bk = (const float*)d_in[4];
    const float* Wv = (const float*)d_in[5];
    const float* bv = (const float*)d_in[6];
    const float* Wo = (const float*)d_in[7];
    const float* bo = (const float*)d_in[8];

    float* out  = (float*)d_out;                    // B*T*HID
    float* attn = out + (long)BTc * HIDc;           // B*T*T

    // workspace: xb | Wqt | Wkt | Wvt | qb | kb | v | linv | o1  (~59 MB)
    unsigned short* xb  = (unsigned short*)d_ws;
    unsigned short* Wqt = xb  + (long)BTc * HIDc;
    unsigned short* Wkt = Wqt + (long)HIDc * HIDc;
    unsigned short* Wvt = Wkt + (long)HIDc * HIDc;
    unsigned short* qb  = Wvt + (long)HSc * HIDc;
    unsigned short* kb  = qb  + (long)BTc * HIDc;
    float* v    = (float*)(kb + (long)BTc * HIDc);
    float* linv = v    + (long)BTc * HSc;
    float* o1   = linv + (long)Bc * NHc * Tt;

    dim3 blk(256);

    // prep: casts + weight transposes + accum-output init (ws is poisoned)
    cast_bf16<<<dim3((BTc * HIDc) / 1024), blk, 0, stream>>>(x, xb, (long)BTc * HIDc);
    transpose_cast<<<dim3(32, 32), blk, 0, stream>>>(Wq, Wqt, HIDc, HIDc);
    transpose_cast<<<dim3(32, 32), blk, 0, stream>>>(Wk, Wkt, HIDc, HIDc);
    transpose_cast<<<dim3(32, 2),  blk, 0, stream>>>(Wv, Wvt, HIDc, HSc);
    init_bias64<<<dim3((BTc * HSc) / 256), blk, 0, stream>>>(v,  bv,      (long)BTc * HSc);
    init_bias64<<<dim3((BTc * HSc) / 256), blk, 0, stream>>>(o1, nullptr, (long)BTc * HSc);

    // Q/K projections (bf16 MFMA, XCD-swizzled 1-D grids).
    gemm_bt_bf16<<<dim3(512), blk, 0, stream>>>(xb, Wqt, bq, qb, BTc, HIDc, HIDc, QSCALE);
    gemm_bt_bf16<<<dim3(512), blk, 0, stream>>>(xb, Wkt, bk, kb, BTc, HIDc, HIDc, 1.0f);

    // V projection: bf16 MFMA split-K (atomics into fp32 v, bias-preinit'd)
    gemm_v_bf16<<<dim3(256), blk, 0, stream>>>(xb, Wvt, v);

    // pass 1: softmax denominators (XCD-swizzled 1-D grid)
    attn_denom<<<dim3(1024), blk, 0, stream>>>(qb, kb, linv);

    // pass 2 (fused 128x128, 8 waves): attn tile + P@V accumulation into o1
    attn_avg_w<<<dim3(1024), dim3(512), 0, stream>>>(qb, kb, linv, v, attn, o1);

    // out = o1 @ Wo + bo
    gemm_f32<<<dim3(HIDc / 64, BTc / 64), blk, 0, stream>>>(o1, Wo, bo, out, BTc, HIDc, HSc);
}

// Round 15
// 440.984 us; speedup vs baseline: 1.0984x; 1.0189x over previous
//
#include <hip/hip_runtime.h>
#include <math.h>

// Problem constants (fixed by the reference)
#define Bc   4
#define Tt   2048
#define HIDc 1024
#define NHc  16
#define HSc  64
#define BTc  (Bc * Tt)          // 8192
#define QSCALE 0.18033688011112042f   // 0.125 * log2(e): folded into q so exp(s/8)=2^acc

typedef __attribute__((ext_vector_type(8))) short bf16x8;   // 8 bf16 = 4 VGPRs
typedef __attribute__((ext_vector_type(4))) float f32x4;

__device__ __forceinline__ unsigned short f2bf(float f) {
    unsigned u = __float_as_uint(f);
    u = u + 0x7FFFu + ((u >> 16) & 1u);   // round-to-nearest-even
    return (unsigned short)(u >> 16);
}

__device__ __forceinline__ float fexp2(float x) {
#if __has_builtin(__builtin_amdgcn_exp2f)
    return __builtin_amdgcn_exp2f(x);
#else
    float r; asm("v_exp_f32 %0, %1" : "=v"(r) : "v"(x)); return r;
#endif
}

// ---------------------------------------------------------------------------
// fp32 GEMM (Wo epilogue): C = A @ B + bias, 64x64 tile.
// ---------------------------------------------------------------------------
__global__ __launch_bounds__(256) void gemm_f32(
    const float* __restrict__ A, const float* __restrict__ Bm,
    const float* __restrict__ bias, float* __restrict__ C,
    int M, int N, int K)
{
    __shared__ float As[16][64];
    __shared__ float Bs[16][64];

    const int tid  = threadIdx.x;
    const int tx   = tid & 15;
    const int ty   = tid >> 4;
    const int row0 = blockIdx.y * 64;
    const int col0 = blockIdx.x * 64;

    const int la_r = tid >> 2;
    const int la_c = (tid & 3) << 2;
    const int lb_r = tid >> 4;
    const int lb_c = (tid & 15) << 2;

    float acc[4][4] = {};

    for (int k0 = 0; k0 < K; k0 += 16) {
        float4 av = *(const float4*)&A[(long)(row0 + la_r) * K + k0 + la_c];
        float4 bv = *(const float4*)&Bm[(long)(k0 + lb_r) * N + col0 + lb_c];
        __syncthreads();
        As[la_c + 0][la_r] = av.x;
        As[la_c + 1][la_r] = av.y;
        As[la_c + 2][la_r] = av.z;
        As[la_c + 3][la_r] = av.w;
        *(float4*)&Bs[lb_r][lb_c] = bv;
        __syncthreads();
#pragma unroll
        for (int kk = 0; kk < 16; ++kk) {
            float4 a = *(float4*)&As[kk][ty << 2];
            float4 b = *(float4*)&Bs[kk][tx << 2];
            float ar[4] = {a.x, a.y, a.z, a.w};
            float br[4] = {b.x, b.y, b.z, b.w};
#pragma unroll
            for (int i = 0; i < 4; ++i)
#pragma unroll
                for (int j = 0; j < 4; ++j)
                    acc[i][j] = fmaf(ar[i], br[j], acc[i][j]);
        }
    }

    float4 bvv = make_float4(0.f, 0.f, 0.f, 0.f);
    if (bias) bvv = *(const float4*)&bias[col0 + (tx << 2)];
#pragma unroll
    for (int i = 0; i < 4; ++i) {
        int m = row0 + (ty << 2) + i;
        float4 o;
        o.x = acc[i][0] + bvv.x;
        o.y = acc[i][1] + bvv.y;
        o.z = acc[i][2] + bvv.z;
        o.w = acc[i][3] + bvv.w;
        *(float4*)&C[(long)m * N + col0 + (tx << 2)] = o;
    }
}

// ---------------------------------------------------------------------------
// Init C(rows,64) with broadcast bias (or zero).
// ---------------------------------------------------------------------------
__global__ __launch_bounds__(256) void init_bias64(
    float* __restrict__ C, const float* __restrict__ bias, long n)
{
    long idx = (long)blockIdx.x * 256 + threadIdx.x;
    if (idx < n) C[idx] = bias ? bias[idx & 63] : 0.f;
}

// ---------------------------------------------------------------------------
// Prep: cast fp32 -> bf16
// ---------------------------------------------------------------------------
__global__ __launch_bounds__(256) void cast_bf16(
    const float* __restrict__ src, unsigned short* __restrict__ dst, long n)
{
    long i = ((long)blockIdx.x * 256 + threadIdx.x) * 4;
    if (i >= n) return;
    float4 v = *(const float4*)&src[i];
    ushort4 o;
    o.x = f2bf(v.x); o.y = f2bf(v.y); o.z = f2bf(v.z); o.w = f2bf(v.w);
    *(ushort4*)&dst[i] = o;
}

// ---------------------------------------------------------------------------
// Prep: transpose + cast: Wt[n][k] = (bf16) W[k][n].  W is RxC, Wt is CxR.
// grid: (R/32, C/32)
// ---------------------------------------------------------------------------
__global__ __launch_bounds__(256) void transpose_cast(
    const float* __restrict__ W, unsigned short* __restrict__ Wt, int R, int C)
{
    __shared__ float t[32][33];
    const int k0 = blockIdx.x * 32, n0 = blockIdx.y * 32;
    const int c = threadIdx.x & 31, r = threadIdx.x >> 5;  // r: 0..7
#pragma unroll
    for (int rr = r; rr < 32; rr += 8)
        t[rr][c] = W[(long)(k0 + rr) * C + n0 + c];
    __syncthreads();
#pragma unroll
    for (int rr = r; rr < 32; rr += 8)
        Wt[(long)(n0 + rr) * R + k0 + c] = f2bf(t[c][rr]);
}

// ---------------------------------------------------------------------------
// bf16 MFMA GEMM, B^T input: C(M,N) bf16 = ((A @ Bt^T) + bias) * oscale
// 128x128 tile, BK=64, 256 threads (4 waves, 64x64 quadrant each).
// 1-D grid 512, XCD-swizzled (halved FETCH in round 4).
// (No setprio here: m190 showed it slightly hurts lockstep GEMM.)
// ---------------------------------------------------------------------------
__global__ __launch_bounds__(256) void gemm_bt_bf16(
    const unsigned short* __restrict__ A, const unsigned short* __restrict__ Bt,
    const float* __restrict__ bias, unsigned short* __restrict__ C,
    int M, int N, int K, float oscale)
{
    __shared__ unsigned short As[128][72];
    __shared__ unsigned short Bs[128][72];

    const int gid = blockIdx.x;
    const int xcd = gid & 7, ii = gid >> 3;          // ii: 0..63
    const int row0 = (xcd * 8 + (ii >> 3)) * 128;    // row-tile 0..63
    const int col0 = (ii & 7) * 128;                 // col-tile 0..7

    const int tid  = threadIdx.x;
    const int w  = tid >> 6, L = tid & 63;
    const int wm = (w & 1) * 64, wn = (w >> 1) * 64;
    const int lr = tid >> 3;          // staging row (0..31, +32 steps)
    const int lc = (tid & 7) * 8;     // staging dim chunk (8 bf16 = 16 B)
    const int ml = L & 15, q8 = (L >> 4) * 8, q4 = (L >> 4) * 4;

    f32x4 acc[4][4];
#pragma unroll
    for (int i = 0; i < 4; ++i)
#pragma unroll
        for (int j = 0; j < 4; ++j)
            acc[i][j] = (f32x4){0.f, 0.f, 0.f, 0.f};

    for (int k0 = 0; k0 < K; k0 += 64) {
        __syncthreads();
#pragma unroll
        for (int rr = 0; rr < 128; rr += 32) {
            *(float4*)&As[lr + rr][lc] = *(const float4*)&A[(long)(row0 + lr + rr) * K + k0 + lc];
            *(float4*)&Bs[lr + rr][lc] = *(const float4*)&Bt[(long)(col0 + lr + rr) * K + k0 + lc];
        }
        __syncthreads();
#pragma unroll
        for (int kk = 0; kk < 64; kk += 32) {
            bf16x8 a[4], b[4];
#pragma unroll
            for (int i = 0; i < 4; ++i) a[i] = *(bf16x8*)&As[wm + i * 16 + ml][kk + q8];
#pragma unroll
            for (int j = 0; j < 4; ++j) b[j] = *(bf16x8*)&Bs[wn + j * 16 + ml][kk + q8];
#pragma unroll
            for (int i = 0; i < 4; ++i)
#pragma unroll
                for (int j = 0; j < 4; ++j)
                    acc[i][j] = __builtin_amdgcn_mfma_f32_16x16x32_bf16(a[i], b[j], acc[i][j], 0, 0, 0);
        }
    }

#pragma unroll
    for (int j = 0; j < 4; ++j) {
        const int col = col0 + wn + j * 16 + ml;
        const float bj = bias ? bias[col] : 0.f;
#pragma unroll
        for (int i = 0; i < 4; ++i) {
#pragma unroll
            for (int r = 0; r < 4; ++r) {
                const int row = row0 + wm + i * 16 + q4 + r;
                C[(long)row * N + col] = f2bf((acc[i][j][r] + bj) * oscale);
            }
        }
    }
}

// ---------------------------------------------------------------------------
// V projection, bf16 MFMA split-K: C(8192,64) fp32 += xb(8192,1024)[kchunk] @ Wvt^T
// 1-D grid 256, XCD-swizzled. Caller pre-inits C with bias.
// ---------------------------------------------------------------------------
__global__ __launch_bounds__(256) void gemm_v_bf16(
    const unsigned short* __restrict__ A, const unsigned short* __restrict__ Bt,
    float* __restrict__ C)
{
    __shared__ unsigned short As[128][72];
    __shared__ unsigned short Bs[64][72];

    const int gid = blockIdx.x;
    const int xcd = gid & 7, ii = gid >> 3;          // ii: 0..31
    const int row0 = (xcd * 8 + (ii >> 2)) * 128;    // row-tile 0..63
    const int kbeg = (ii & 3) * 256;                 // k-chunk 0..3

    const int tid  = threadIdx.x;
    const int w = tid >> 6, L = tid & 63;
    const int ml = L & 15, q8 = (L >> 4) * 8, q4 = (L >> 4) * 4;
    const int ar = tid >> 3, ac = (tid & 7) * 8;
    const int br = tid >> 2, bc = (tid & 3) * 16;

    f32x4 acc[2][4];
#pragma unroll
    for (int i = 0; i < 2; ++i)
#pragma unroll
        for (int j = 0; j < 4; ++j) acc[i][j] = (f32x4){0.f, 0.f, 0.f, 0.f};

    for (int k0 = kbeg; k0 < kbeg + 256; k0 += 64) {
        __syncthreads();
#pragma unroll
        for (int rr = 0; rr < 128; rr += 32)
            *(float4*)&As[ar + rr][ac] = *(const float4*)&A[(long)(row0 + ar + rr) * HIDc + k0 + ac];
        *(float4*)&Bs[br][bc]     = *(const float4*)&Bt[(long)br * HIDc + k0 + bc];
        *(float4*)&Bs[br][bc + 8] = *(const float4*)&Bt[(long)br * HIDc + k0 + bc + 8];
        __syncthreads();
#pragma unroll
        for (int kk = 0; kk < 64; kk += 32) {
            bf16x8 a[2], b[4];
#pragma unroll
            for (int i = 0; i < 2; ++i) a[i] = *(bf16x8*)&As[w * 32 + i * 16 + ml][kk + q8];
#pragma unroll
            for (int j = 0; j < 4; ++j) b[j] = *(bf16x8*)&Bs[j * 16 + ml][kk + q8];
#pragma unroll
            for (int i = 0; i < 2; ++i)
#pragma unroll
                for (int j = 0; j < 4; ++j)
                    acc[i][j] = __builtin_amdgcn_mfma_f32_16x16x32_bf16(a[i], b[j], acc[i][j], 0, 0, 0);
        }
    }

#pragma unroll
    for (int i = 0; i < 2; ++i)
#pragma unroll
        for (int j = 0; j < 4; ++j)
#pragma unroll
            for (int r = 0; r < 4; ++r)
                atomicAdd(&C[(long)(row0 + w * 32 + i * 16 + q4 + r) * 64 + j * 16 + ml], acc[i][j][r]);
}

// ---------------------------------------------------------------------------
// Attention pass 1: softmax denominators. q pre-scaled by QSCALE so
// exp(s/8) = 2^(q'.k). 1-D grid 1024, XCD-swizzled.
// Round-15: T5 s_setprio(1) around the MFMA cluster -- co-resident blocks
// sit at different phases, so the CU scheduler can favor the block that is
// in its MFMA window over blocks issuing staging loads (m191: +4-7% attn).
// ---------------------------------------------------------------------------
__global__ __launch_bounds__(256) void attn_denom(
    const unsigned short* __restrict__ qb, const unsigned short* __restrict__ kb,
    float* __restrict__ linv)
{
    const int gid = blockIdx.x;
    const int xcd = gid & 7, ii = gid >> 3;   // ii: 0..127
    const int bh  = xcd * 8 + (ii >> 4);      // 0..63
    const int qt  = ii & 15;
    const int b   = bh >> 4, h = bh & 15;

    __shared__ unsigned short Qs[128][72];
    __shared__ unsigned short Ks[64][72];

    const int tid = threadIdx.x;
    const int w = tid >> 6, L = tid & 63;
    const int ml = L & 15, q8 = (L >> 4) * 8, q4 = (L >> 4) * 4;
    const int ar = tid >> 3, ac = (tid & 7) * 8;
    const int kr = tid >> 2, kc = (tid & 3) * 16;

    // Stage 128-row Q slice once.
#pragma unroll
    for (int rr = 0; rr < 128; rr += 32)
        *(float4*)&Qs[ar + rr][ac] =
            *(const float4*)&qb[(long)(b * Tt + qt * 128 + ar + rr) * HIDc + h * HSc + ac];

    const unsigned short* kbase = kb + ((long)(b * Tt + kr) * HIDc + h * HSc + kc);
    float4 v0 = *(const float4*)kbase;
    float4 v1 = *(const float4*)(kbase + 8);

    float lacc[2][4] = {};

    for (int kt = 0; kt < Tt / 64; ++kt) {
        *(float4*)&Ks[kr][kc]     = v0;
        *(float4*)&Ks[kr][kc + 8] = v1;
        if (kt + 1 < Tt / 64) {
            const unsigned short* s = kbase + (long)(kt + 1) * 64 * HIDc;
            v0 = *(const float4*)s;
            v1 = *(const float4*)(s + 8);
        }
        __syncthreads();   // Ks(kt) (and Qs, first iter) visible

        f32x4 acc[2][4];
#pragma unroll
        for (int i = 0; i < 2; ++i)
#pragma unroll
            for (int j = 0; j < 4; ++j) acc[i][j] = (f32x4){0.f, 0.f, 0.f, 0.f};
        __builtin_amdgcn_s_setprio(1);
#pragma unroll
        for (int kk = 0; kk < 64; kk += 32) {
            bf16x8 a[2], bfr[4];
#pragma unroll
            for (int i = 0; i < 2; ++i) a[i] = *(bf16x8*)&Qs[w * 32 + i * 16 + ml][kk + q8];
#pragma unroll
            for (int j = 0; j < 4; ++j) bfr[j] = *(bf16x8*)&Ks[j * 16 + ml][kk + q8];
#pragma unroll
            for (int i = 0; i < 2; ++i)
#pragma unroll
                for (int j = 0; j < 4; ++j)
                    acc[i][j] = __builtin_amdgcn_mfma_f32_16x16x32_bf16(a[i], bfr[j], acc[i][j], 0, 0, 0);
        }
        __builtin_amdgcn_s_setprio(0);
#pragma unroll
        for (int i = 0; i < 2; ++i)
#pragma unroll
            for (int j = 0; j < 4; ++j)
#pragma unroll
                for (int r = 0; r < 4; ++r)
                    lacc[i][r] += fexp2(acc[i][j][r]);
        __syncthreads();   // all reads done before next Ks write
    }

#pragma unroll
    for (int i = 0; i < 2; ++i)
#pragma unroll
        for (int r = 0; r < 4; ++r) {
            float v = lacc[i][r];
            v += __shfl_xor(v, 1, 16);
            v += __shfl_xor(v, 2, 16);
            v += __shfl_xor(v, 4, 16);
            v += __shfl_xor(v, 8, 16);
            if (ml == 0)
                linv[((long)(b * NHc + h)) * Tt + qt * 128 + w * 32 + i * 16 + q4 + r] =
                    1.0f / (v * (float)NHc);
        }
}

// ---------------------------------------------------------------------------
// Attention pass 2 (FUSED, 128x128 tile, 512 threads / 8 waves) -- round-6
// configuration (best measured, 442.0 us total) + T5 s_setprio around the
// MFMA clusters (QK^T and PV). All else identical to r6.
// ---------------------------------------------------------------------------
__global__ __launch_bounds__(512) void attn_avg_w(
    const unsigned short* __restrict__ qb, const unsigned short* __restrict__ kb,
    const float* __restrict__ linv, const float* __restrict__ v,
    float* __restrict__ attn, float* __restrict__ o1)
{
    const int gid = blockIdx.x;
    const int xcd = gid & 7, ii = gid >> 3;   // ii: 0..127
    const int b = xcd >> 1, qhalf = xcd & 1;
    const int t = ii >> 4, u = ii & 15;       // t: 0..7 (2q x 4k supertiles)
    const int qt  = qhalf * 8 + (t & 1) * 4 + (u >> 2);   // 0..15
    const int ktg = (t >> 1) * 4 + (u & 3);               // 0..15

    // LDS overlay: phase1 {Qs 128x72, Ks 128x72, invsAll 16x128} (45056 B)
    //              phase2 {Ps 128x136 @0, Vst 64x136 @34816}     (52224 B)
    __shared__ __align__(16) unsigned char smem[52224];
    unsigned short (*Qs)[72]   = (unsigned short(*)[72])smem;             // 18432 B
    unsigned short (*Ks)[72]   = (unsigned short(*)[72])(smem + 18432);   // 18432 B
    float (*invsAll)[128]      = (float(*)[128])(smem + 36864);           // 8192 B
    unsigned short (*Ps)[136]  = (unsigned short(*)[136])smem;            // 34816 B
    unsigned short (*Vst)[136] = (unsigned short(*)[136])(smem + 34816);  // 17408 B

    const int tid = threadIdx.x;
    const int w = tid >> 6, L = tid & 63;
    const int ml = L & 15, q8 = (L >> 4) * 8, q4 = (L >> 4) * 4;
    const int wq = (w >> 2) * 64;     // wave q-offset, scores (2 strips of 64)
    const int wk = (w & 3) * 32;      // wave k-offset, scores (4 strips of 32)
    const int sr = tid >> 2, sc = (tid & 3) * 16;   // staging: row 0..127, 16-col chunk

    // Stage all 16 heads' 1/(l*NH) once: thread t -> head t>>5, rows (t&31)*4..+3
    {
        const int hh = tid >> 5, r4 = (tid & 31) * 4;
        *(float4*)&invsAll[hh][r4] =
            *(const float4*)&linv[((long)(b * NHc + hh)) * Tt + qt * 128 + r4];
    }

    const unsigned short* qbase = qb + ((long)(b * Tt + qt * 128 + sr) * HIDc + sc);
    const unsigned short* kbase = kb + ((long)(b * Tt + ktg * 128 + sr) * HIDc + sc);

    // Prefetch head 0 into registers (2 float4 Q + 2 float4 K per thread).
    float4 qv[2], kv[2];
#pragma unroll
    for (int c = 0; c < 2; ++c) {
        qv[c] = *(const float4*)(qbase + c * 8);
        kv[c] = *(const float4*)(kbase + c * 8);
    }

    float pacc[4][2][4] = {};

    for (int h = 0; h < NHc; ++h) {
        // Write LDS from regs(h), then issue loads for h+1 (T14: latency
        // hides under this head's MFMA+exp).
#pragma unroll
        for (int c = 0; c < 2; ++c) {
            *(float4*)&Qs[sr][sc + c * 8] = qv[c];
            *(float4*)&Ks[sr][sc + c * 8] = kv[c];
        }
        if (h + 1 < NHc) {
            const unsigned short* sq = qbase + (h + 1) * HSc;
            const unsigned short* sk = kbase + (h + 1) * HSc;
#pragma unroll
            for (int c = 0; c < 2; ++c) {
                qv[c] = *(const float4*)(sq + c * 8);
                kv[c] = *(const float4*)(sk + c * 8);
            }
        }
        __syncthreads();   // LDS(h) visible (first iter also covers invsAll)

        f32x4 acc[4][2];
#pragma unroll
        for (int i = 0; i < 4; ++i)
#pragma unroll
            for (int j = 0; j < 2; ++j) acc[i][j] = (f32x4){0.f, 0.f, 0.f, 0.f};
        __builtin_amdgcn_s_setprio(1);
#pragma unroll
        for (int kk = 0; kk < 64; kk += 32) {
            bf16x8 a[4], bfr[2];
#pragma unroll
            for (int i = 0; i < 4; ++i) a[i]   = *(bf16x8*)&Qs[wq + i * 16 + ml][kk + q8];
#pragma unroll
            for (int j = 0; j < 2; ++j) bfr[j] = *(bf16x8*)&Ks[wk + j * 16 + ml][kk + q8];
#pragma unroll
            for (int i = 0; i < 4; ++i)
#pragma unroll
                for (int j = 0; j < 2; ++j)
                    acc[i][j] = __builtin_amdgcn_mfma_f32_16x16x32_bf16(a[i], bfr[j], acc[i][j], 0, 0, 0);
        }
        __builtin_amdgcn_s_setprio(0);
        float ivr[4][4];
#pragma unroll
        for (int i = 0; i < 4; ++i)
            *(float4*)&ivr[i][0] = *(const float4*)&invsAll[h][wq + i * 16 + q4];
#pragma unroll
        for (int i = 0; i < 4; ++i)
#pragma unroll
            for (int j = 0; j < 2; ++j)
#pragma unroll
                for (int r = 0; r < 4; ++r)
                    pacc[i][j][r] += fexp2(acc[i][j][r]) * ivr[i][r];
        __syncthreads();   // reads of LDS(h) done before next head's write
    }
    // (trailing barrier: all Qs/Ks/invsAll reads complete -> overlay safe)

    // Epilogue: write attn (fp32) + Ps (bf16) for the PV step.
#pragma unroll
    for (int i = 0; i < 4; ++i)
#pragma unroll
        for (int j = 0; j < 2; ++j)
#pragma unroll
            for (int r = 0; r < 4; ++r) {
                const int qrow = wq + i * 16 + q4 + r;
                const int col  = wk + j * 16 + ml;
                attn[((long)(b * Tt + qt * 128 + qrow)) * Tt + ktg * 128 + col] = pacc[i][j][r];
                Ps[qrow][col] = f2bf(pacc[i][j][r]);
            }
    // Stage V^T: Vst[d][k] over k-range of this tile.
#pragma unroll
    for (int e = tid; e < 8192; e += 512) {
        const int r = e >> 6, d = e & 63;
        Vst[d][r] = f2bf(v[((long)(b * Tt + ktg * 128 + r)) * 64 + d]);
    }
    __syncthreads();

    // U(128x64) = P(128x128) @ V(128x64); wave: 32 q-rows x 32 d-cols.
    const int pq = (w >> 1) * 32, wd = (w & 1) * 32;
    f32x4 uacc[2][2];
#pragma unroll
    for (int i = 0; i < 2; ++i)
#pragma unroll
        for (int j = 0; j < 2; ++j) uacc[i][j] = (f32x4){0.f, 0.f, 0.f, 0.f};
    __builtin_amdgcn_s_setprio(1);
#pragma unroll
    for (int kk = 0; kk < 128; kk += 32) {
        bf16x8 a2[2], bvv[2];
#pragma unroll
        for (int i = 0; i < 2; ++i) a2[i]  = *(bf16x8*)&Ps[pq + i * 16 + ml][kk + q8];
#pragma unroll
        for (int j = 0; j < 2; ++j) bvv[j] = *(bf16x8*)&Vst[wd + j * 16 + ml][kk + q8];
#pragma unroll
        for (int i = 0; i < 2; ++i)
#pragma unroll
            for (int j = 0; j < 2; ++j)
                uacc[i][j] = __builtin_amdgcn_mfma_f32_16x16x32_bf16(a2[i], bvv[j], uacc[i][j], 0, 0, 0);
    }
    __builtin_amdgcn_s_setprio(0);
#pragma unroll
    for (int i = 0; i < 2; ++i)
#pragma unroll
        for (int j = 0; j < 2; ++j)
#pragma unroll
            for (int r = 0; r < 4; ++r)
                atomicAdd(&o1[((long)(b * Tt + qt * 128 + pq + i * 16 + q4 + r)) * 64 + wd + j * 16 + ml],
                          uacc[i][j][r]);
}

// ---------------------------------------------------------------------------
extern "C" void kernel_launch(void* const* d_in, const int* in_sizes, int n_in,
                              void* d_out, int out_size, void* d_ws, size_t ws_size,
                              hipStream_t stream)
{
    const float* x  = (const float*)d_in[0];
    const float* Wq = (const float*)d_in[1];
    const float* bq = (const float*)d_in[2];
    const float* Wk = (const float*)d_in[3];
    const float* bk = (const float*)d_in[4];
    const float* Wv = (const float*)d_in[5];
    const float* bv = (const float*)d_in[6];
    const float* Wo = (const float*)d_in[7];
    const float* bo = (const float*)d_in[8];

    float* out  = (float*)d_out;                    // B*T*HID
    float* attn = out + (long)BTc * HIDc;           // B*T*T

    // workspace: xb | Wqt | Wkt | Wvt | qb | kb | v | linv | o1  (~59 MB)
    unsigned short* xb  = (unsigned short*)d_ws;
    unsigned short* Wqt = xb  + (long)BTc * HIDc;
    unsigned short* Wkt = Wqt + (long)HIDc * HIDc;
    unsigned short* Wvt = Wkt + (long)HIDc * HIDc;
    unsigned short* qb  = Wvt + (long)HSc * HIDc;
    unsigned short* kb  = qb  + (long)BTc * HIDc;
    float* v    = (float*)(kb + (long)BTc * HIDc);
    float* linv = v    + (long)BTc * HSc;
    float* o1   = linv + (long)Bc * NHc * Tt;

    dim3 blk(256);

    // prep: casts + weight transposes + accum-output init (ws is poisoned)
    cast_bf16<<<dim3((BTc * HIDc) / 1024), blk, 0, stream>>>(x, xb, (long)BTc * HIDc);
    transpose_cast<<<dim3(32, 32), blk, 0, stream>>>(Wq, Wqt, HIDc, HIDc);
    transpose_cast<<<dim3(32, 32), blk, 0, stream>>>(Wk, Wkt, HIDc, HIDc);
    transpose_cast<<<dim3(32, 2),  blk, 0, stream>>>(Wv, Wvt, HIDc, HSc);
    init_bias64<<<dim3((BTc * HSc) / 256), blk, 0, stream>>>(v,  bv,      (long)BTc * HSc);
    init_bias64<<<dim3((BTc * HSc) / 256), blk, 0, stream>>>(o1, nullptr, (long)BTc * HSc);

    // Q/K projections (bf16 MFMA, XCD-swizzled 1-D grids).
    gemm_bt_bf16<<<dim3(512), blk, 0, stream>>>(xb, Wqt, bq, qb, BTc, HIDc, HIDc, QSCALE);
    gemm_bt_bf16<<<dim3(512), blk, 0, stream>>>(xb, Wkt, bk, kb, BTc, HIDc, HIDc, 1.0f);

    // V projection: bf16 MFMA split-K (atomics into fp32 v, bias-preinit'd)
    gemm_v_bf16<<<dim3(256), blk, 0, stream>>>(xb, Wvt, v);

    // pass 1: softmax denominators (XCD-swizzled 1-D grid, setprio MFMA)
    attn_denom<<<dim3(1024), blk, 0, stream>>>(qb, kb, linv);

    // pass 2 (fused 128x128, 8 waves, setprio MFMA): attn + P@V -> o1
    attn_avg_w<<<dim3(1024), dim3(512), 0, stream>>>(qb, kb, linv, v, attn, o1);

    // out = o1 @ Wo + bo
    gemm_f32<<<dim3(HIDc / 64, BTc / 64), blk, 0, stream>>>(o1, Wo, bo, out, BTc, HIDc, HSc);
}